// Round 3
// baseline (103.064 us; speedup 1.0000x reference)
//
#include <hip/hip_runtime.h>
#include <hip/hip_cooperative_groups.h>

namespace cg = cooperative_groups;

#define N_NODES 100000
#define D 128
#define N_EDGES 1000000
#define NBLOCKS 1024
#define NTHREADS 256

// Fused: phase A computes per-node scores into d_ws, grid sync, phase B
// does per-edge sigmoid(s_src[src] + s_dst[dst]). Edge indices are
// preloaded into registers BEFORE phase A so the 8MB idx stream overlaps
// the 51.2MB z stream.
__global__ void __launch_bounds__(256, 4) fused_kernel(
    const float* __restrict__ z, const int* __restrict__ idx,
    const float* __restrict__ W, const float* __restrict__ b,
    float* __restrict__ s, float* __restrict__ out) {
  int tid = blockIdx.x * blockDim.x + threadIdx.x;  // 0 .. 262143

  // ---- preload edge indices (complete during phase A) ----
  int4 sv = make_int4(0, 0, 0, 0), dv = make_int4(0, 0, 0, 0);
  const bool has_edges = tid < (N_EDGES / 4);
  if (has_edges) {
    sv = reinterpret_cast<const int4*>(idx)[tid];            // src row
    dv = reinterpret_cast<const int4*>(idx + N_EDGES)[tid];  // dst row
  }

  // ---- phase A: node scores, 32 lanes per node, 2 nodes per wave ----
  int wave = tid >> 6;            // 0 .. 4095
  int lane = threadIdx.x & 63;
  int half = lane >> 5;
  int l32  = lane & 31;
  const float4 ws = reinterpret_cast<const float4*>(W)[l32];       // W_src
  const float4 wd = reinterpret_cast<const float4*>(W)[32 + l32];  // W_dst
  const float bias = b[0];
  const int npairs = N_NODES / 2;             // 50000 (N_NODES even)
  const int wstride = (NBLOCKS * NTHREADS) / 64;  // 4096 waves

  for (int p = wave; p < npairs; p += wstride) {
    int node = p * 2 + half;
    const float4 zv =
        reinterpret_cast<const float4*>(z + (size_t)node * D)[l32];
    float a = zv.x * ws.x + zv.y * ws.y + zv.z * ws.z + zv.w * ws.w;
    float c = zv.x * wd.x + zv.y * wd.y + zv.z * wd.z + zv.w * wd.w;
    #pragma unroll
    for (int off = 16; off >= 1; off >>= 1) {
      a += __shfl_xor(a, off, 64);
      c += __shfl_xor(c, off, 64);
    }
    if (l32 == 0) {
      s[node] = a + bias;        // bias folded into src score
      s[N_NODES + node] = c;
    }
  }

  cg::this_grid().sync();

  // ---- phase B: edges (indices already in registers) ----
  if (has_edges) {
    const float* __restrict__ sd = s + N_NODES;
    float l0 = s[sv.x] + sd[dv.x];
    float l1 = s[sv.y] + sd[dv.y];
    float l2 = s[sv.z] + sd[dv.z];
    float l3 = s[sv.w] + sd[dv.w];
    float4 o;
    o.x = 1.0f / (1.0f + __expf(-l0));
    o.y = 1.0f / (1.0f + __expf(-l1));
    o.z = 1.0f / (1.0f + __expf(-l2));
    o.w = 1.0f / (1.0f + __expf(-l3));
    reinterpret_cast<float4*>(out)[tid] = o;
  }
}

extern "C" void kernel_launch(void* const* d_in, const int* in_sizes, int n_in,
                              void* d_out, int out_size, void* d_ws, size_t ws_size,
                              hipStream_t stream) {
  const float* z   = (const float*)d_in[0];
  const int*   idx = (const int*)d_in[1];
  const float* W   = (const float*)d_in[2];
  const float* b   = (const float*)d_in[3];
  float* out = (float*)d_out;
  float* s   = (float*)d_ws;   // 2 * N_NODES floats = 800 KB

  void* args[] = {(void*)&z, (void*)&idx, (void*)&W, (void*)&b,
                  (void*)&s, (void*)&out};
  hipLaunchCooperativeKernel((void*)fused_kernel, dim3(NBLOCKS),
                             dim3(NTHREADS), args, 0, stream);
}

// Round 4
// 24.739 us; speedup vs baseline: 4.1660x; 4.1660x over previous
//
#include <hip/hip_runtime.h>
#include <hip/hip_bf16.h>

#define N_NODES 100000
#define D 128
#define N_EDGES 1000000

// Kernel 1: per-node scores. 16 lanes per node, 4 nodes/wave.
// s[0 .. n_nodes)        = z[n] . W[0:128] + b   (src score, bias folded in)
// s[n_nodes .. 2n_nodes) = z[n] . W[128:256]     (dst score)
__global__ void __launch_bounds__(256) node_scores_kernel(
    const float* __restrict__ z, const float* __restrict__ W,
    const float* __restrict__ b, float* __restrict__ s) {
  int tid  = blockIdx.x * blockDim.x + threadIdx.x;
  int wave = tid >> 6;           // global wave id, 0..24999
  int lane = threadIdx.x & 63;
  int sub  = lane >> 4;          // node within wave (0..3)
  int l16  = lane & 15;          // lane within 16-lane group
  int node = wave * 4 + sub;     // N_NODES % 4 == 0, grid exact -> no guard

  // lane covers features [4*l16, 4*l16+4) and [64+4*l16, 64+4*l16+4)
  const float4* zrow = reinterpret_cast<const float4*>(z + (size_t)node * D);
  const float4 z0 = zrow[l16];
  const float4 z1 = zrow[16 + l16];

  const float4* Wv = reinterpret_cast<const float4*>(W);
  const float4 ws0 = Wv[l16],      ws1 = Wv[16 + l16];   // W_src halves
  const float4 wd0 = Wv[32 + l16], wd1 = Wv[48 + l16];   // W_dst halves

  float a = z0.x * ws0.x + z0.y * ws0.y + z0.z * ws0.z + z0.w * ws0.w
          + z1.x * ws1.x + z1.y * ws1.y + z1.z * ws1.z + z1.w * ws1.w;
  float c = z0.x * wd0.x + z0.y * wd0.y + z0.z * wd0.z + z0.w * wd0.w
          + z1.x * wd1.x + z1.y * wd1.y + z1.z * wd1.z + z1.w * wd1.w;

  // 4-level butterfly within each 16-lane group
  #pragma unroll
  for (int off = 8; off >= 1; off >>= 1) {
    a += __shfl_xor(a, off, 64);
    c += __shfl_xor(c, off, 64);
  }
  if (l16 == 0) {
    s[node] = a + b[0];
    s[N_NODES + node] = c;
  }
}

// Kernel 2: 2 edges per thread -> ~30 waves/CU for gather latency hiding.
__global__ void __launch_bounds__(256) edge_kernel(
    const int* __restrict__ idx, const float* __restrict__ s,
    float* __restrict__ out) {
  int t = blockIdx.x * blockDim.x + threadIdx.x;
  if (t * 2 >= N_EDGES) return;
  const int2 sv = reinterpret_cast<const int2*>(idx)[t];            // src row
  const int2 dv = reinterpret_cast<const int2*>(idx + N_EDGES)[t];  // dst row
  const float* __restrict__ sd = s + N_NODES;

  float l0 = s[sv.x] + sd[dv.x];
  float l1 = s[sv.y] + sd[dv.y];

  float2 o;
  o.x = 1.0f / (1.0f + __expf(-l0));
  o.y = 1.0f / (1.0f + __expf(-l1));
  reinterpret_cast<float2*>(out)[t] = o;
}

extern "C" void kernel_launch(void* const* d_in, const int* in_sizes, int n_in,
                              void* d_out, int out_size, void* d_ws, size_t ws_size,
                              hipStream_t stream) {
  const float* z   = (const float*)d_in[0];
  const int*   idx = (const int*)d_in[1];
  const float* W   = (const float*)d_in[2];
  const float* b   = (const float*)d_in[3];
  float* out = (float*)d_out;
  float* s   = (float*)d_ws;   // 2 * N_NODES floats = 800 KB

  // Kernel 1: 4 nodes/wave, 4 waves/block -> 16 nodes/block, exact grid
  node_scores_kernel<<<N_NODES / 16, 256, 0, stream>>>(z, W, b, s);

  // Kernel 2: 2 edges per thread
  int blocks2 = (N_EDGES / 2 + 255) / 256;  // 1954
  edge_kernel<<<blocks2, 256, 0, stream>>>(idx, s, out);
}